// Round 5
// baseline (25.810 us; speedup 1.0000x reference)
//
#include <hip/hip_runtime.h>

// SparseIF: multi-step integrate-and-fire, soft reset (v_reset=None), th=1.0
//   v += c[t]; spike = (v >= 1) ? 1 : 0; v -= spike;  out[t] = spike
// Shapes: current [T=64, B=32, D=8192] f32, out same. Pure streaming:
// 64 MB in + 64 MB out. Copy-ceiling roofline ~21.3 us @ 6.29 TB/s (m13).
//
// R1: float4, 1 wave/SIMD                  -> 24.15 us (5.56 TB/s)
// R3: float2 + nontemporal (L3 bypass)     -> 26.32 us (regress; nt hurt)
// R4: float2, plain, 2 waves/SIMD          -> 23.93 us (5.61 TB/s)
// R5: scalar f32, 4 waves/SIMD (4096 waves) — max TLP; thread count is
//     pinned to B*D, T-loop is sequentially dependent per neuron.

#define T_STEPS 64
#define N_NEUR  (32 * 8192)      // B*D = 262144 threads

__global__ __launch_bounds__(256)
void sparse_if_kernel(const float* __restrict__ in, float* __restrict__ out) {
    const int tid = blockIdx.x * blockDim.x + threadIdx.x;  // 0..N_NEUR-1
    float v = 0.f;

#pragma unroll
    for (int t = 0; t < T_STEPS; ++t) {
        const int idx = tid + t * N_NEUR;       // < 2^24, fits int
        float c = in[idx];

        v += c;
        const float s = (v >= 1.0f) ? 1.0f : 0.0f;
        v -= s;                                  // soft reset (th = 1.0)

        out[idx] = s;
    }
}

extern "C" void kernel_launch(void* const* d_in, const int* in_sizes, int n_in,
                              void* d_out, int out_size, void* d_ws, size_t ws_size,
                              hipStream_t stream) {
    const float* in  = reinterpret_cast<const float*>(d_in[0]);
    float*       out = reinterpret_cast<float*>(d_out);

    const int threads = 256;
    const int blocks  = N_NEUR / threads;  // 1024 blocks -> 16 waves/CU (4/SIMD)
    sparse_if_kernel<<<blocks, threads, 0, stream>>>(in, out);
}

// Round 6
// 24.909 us; speedup vs baseline: 1.0362x; 1.0362x over previous
//
#include <hip/hip_runtime.h>

// SparseIF: multi-step integrate-and-fire, soft reset (v_reset=None), th=1.0
//   v += c[t]; spike = (v >= 1) ? 1 : 0; v -= spike;  out[t] = spike
// Shapes: current [T=64, B=32, D=8192] f32, out same. Pure streaming:
// 64 MB in + 64 MB out. Copy-pattern ceiling 6.29 TB/s -> ~21.3 us floor.
//
// R1: float4, 1 wave/SIMD                  -> 24.15 us (5.56 TB/s)
// R3: float2 + nontemporal (L3 bypass)     -> 26.32 us (nt hurt)
// R4: float2, plain, 2 blocks/CU launched  -> 23.93 us (5.61 TB/s)
// R5: scalar f32, 16 waves/CU              -> 25.81 us (narrow loads hurt)
// R6: R4 + __launch_bounds__(256,2): force VGPR <= 256 so both blocks/CU
//     are actually CO-RESIDENT (theory: full-unroll VGPR bloat serialized
//     them, making R4 run at 1 wave/SIMD like R1 — explains R4 ~= R1).

#define T_STEPS 64
#define N_NEUR  (32 * 8192)      // B*D = 262144
#define VEC     2
#define NV      (N_NEUR / VEC)   // 131072 2-wide columns

typedef float v2f __attribute__((ext_vector_type(2)));

__global__ __launch_bounds__(256, 2)   // min 2 waves/SIMD -> VGPR cap 256
void sparse_if_kernel(const v2f* __restrict__ in, v2f* __restrict__ out) {
    const int tid = blockIdx.x * blockDim.x + threadIdx.x;  // 0..NV-1
    float vx = 0.f, vy = 0.f;

#pragma unroll
    for (int t = 0; t < T_STEPS; ++t) {
        const int idx = tid + t * NV;           // < 2^23, fits int
        v2f c = in[idx];

        vx += c.x;
        vy += c.y;

        const float sx = (vx >= 1.0f) ? 1.0f : 0.0f;
        const float sy = (vy >= 1.0f) ? 1.0f : 0.0f;

        vx -= sx;   // soft reset (th = 1.0)
        vy -= sy;

        v2f s;
        s.x = sx;
        s.y = sy;
        out[idx] = s;
    }
}

extern "C" void kernel_launch(void* const* d_in, const int* in_sizes, int n_in,
                              void* d_out, int out_size, void* d_ws, size_t ws_size,
                              hipStream_t stream) {
    const v2f* in  = reinterpret_cast<const v2f*>(d_in[0]);
    v2f*       out = reinterpret_cast<v2f*>(d_out);

    const int threads = 256;
    const int blocks  = NV / threads;  // 512 blocks -> 2 blocks/CU
    sparse_if_kernel<<<blocks, threads, 0, stream>>>(in, out);
}

// Round 7
// 24.296 us; speedup vs baseline: 1.0623x; 1.0252x over previous
//
#include <hip/hip_runtime.h>

// SparseIF: multi-step integrate-and-fire, soft reset (v_reset=None), th=1.0
//   v += c[t]; spike = (v >= 1) ? 1 : 0; v -= spike;  out[t] = spike
// Shapes: current [T=64, B=32, D=8192] f32, out same. Pure streaming:
// 64 MB in + 64 MB out. Copy-pattern ceiling 6.29 TB/s -> ~21.3 us floor.
//
// R1: float4, 1 wave/SIMD                  -> 24.15 us (5.56 TB/s)
// R3: float2 + nontemporal (L3 bypass)     -> 26.32 us (nt hurt)
// R4: float2, plain, compiler schedule     -> 23.93 us (5.61 TB/s)  best
// R5: scalar f32, 4 waves/SIMD             -> 25.81 us (narrow loads hurt)
// R6: R4 + launch_bounds(256,2) VGPR cap   -> 24.91 us (cap hurt ILP)
// R7: R4 + explicit 8-deep load/store BURSTS — batch same-direction memory
//     ops so the DRAM path sees long read runs then long write runs,
//     instead of per-timestep read/write alternation.

#define T_STEPS 64
#define N_NEUR  (32 * 8192)      // B*D = 262144
#define VEC     2
#define NV      (N_NEUR / VEC)   // 131072 2-wide columns
#define CH      8                // timesteps per burst

typedef float v2f __attribute__((ext_vector_type(2)));

__global__ __launch_bounds__(256)
void sparse_if_kernel(const v2f* __restrict__ in, v2f* __restrict__ out) {
    const int tid = blockIdx.x * blockDim.x + threadIdx.x;  // 0..NV-1
    float vx = 0.f, vy = 0.f;

#pragma unroll
    for (int tc = 0; tc < T_STEPS / CH; ++tc) {
        v2f c[CH];
        // Burst of CH loads — none depend on v, all issue back-to-back.
#pragma unroll
        for (int k = 0; k < CH; ++k)
            c[k] = in[tid + (tc * CH + k) * NV];

        v2f s[CH];
        // Dependent VALU chain (carried v).
#pragma unroll
        for (int k = 0; k < CH; ++k) {
            vx += c[k].x;
            vy += c[k].y;
            const float sx = (vx >= 1.0f) ? 1.0f : 0.0f;
            const float sy = (vy >= 1.0f) ? 1.0f : 0.0f;
            vx -= sx;   // soft reset (th = 1.0)
            vy -= sy;
            s[k].x = sx;
            s[k].y = sy;
        }

        // Burst of CH stores.
#pragma unroll
        for (int k = 0; k < CH; ++k)
            out[tid + (tc * CH + k) * NV] = s[k];
    }
}

extern "C" void kernel_launch(void* const* d_in, const int* in_sizes, int n_in,
                              void* d_out, int out_size, void* d_ws, size_t ws_size,
                              hipStream_t stream) {
    const v2f* in  = reinterpret_cast<const v2f*>(d_in[0]);
    v2f*       out = reinterpret_cast<v2f*>(d_out);

    const int threads = 256;
    const int blocks  = NV / threads;  // 512 blocks -> 2 blocks/CU
    sparse_if_kernel<<<blocks, threads, 0, stream>>>(in, out);
}